// Round 6
// baseline (219.807 us; speedup 1.0000x reference)
//
#include <hip/hip_runtime.h>

// types
typedef __attribute__((ext_vector_type(8))) short bf16x8;
typedef __attribute__((ext_vector_type(4))) float f32x4;

#define DEVI static __device__ __forceinline__

DEVI unsigned short f2b(float f) {
  union { float f; unsigned u; } v; v.f = f;
  unsigned r = v.u + 0x7fffu + ((v.u >> 16) & 1u);
  return (unsigned short)(r >> 16);
}

typedef const __attribute__((address_space(1))) void* gas1_t;
typedef __attribute__((address_space(3))) void* las3_t;
#define GL16(g, l) __builtin_amdgcn_global_load_lds((gas1_t)(g), (las3_t)(l), 16, 0, 0)

#define WAITVM(N) asm volatile("s_waitcnt vmcnt(" #N ")" ::: "memory")
#define WAITLGKM  asm volatile("s_waitcnt lgkmcnt(0)" ::: "memory")
#define SCHEDBAR  __builtin_amdgcn_sched_barrier(0)

// ---- workspace layout (bytes) ----
#define OFF_WQKV  0ull          // 768*512*2
#define OFF_WR    786432ull     // 512*256*2
#define OFF_BQKV  1048576ull
#define OFF_SCALE 1051648ull
#define OFF_OFF2  1053696ull
#define OFF_XT    2097152ull    // xt bf16 [16][4096][512] = 64 MiB
#define OFF_YT    2097152ull    // yt bf16 [16][4096][256] = 32 MiB (reuses xt after qkv)
#define OFF_Y     35651584ull   // y  bf16 [16][256][4096] = 32 MiB
#define OFF_Q     69206016ull   // qkv bf16: q,k,v each 16777216 u16

// ---------------- P1: x [B][C][S] f32 -> xt [B][S][C] bf16  (+ fused weight prep) ----------------
__global__ __launch_bounds__(256) void k_xt(
    const float* __restrict__ x, unsigned short* __restrict__ xt,
    const float* __restrict__ Wq, const float* __restrict__ bq,
    const float* __restrict__ Wk, const float* __restrict__ bk,
    const float* __restrict__ Wv, const float* __restrict__ bv,
    const float* __restrict__ Wr, const float* __restrict__ br,
    const float* __restrict__ gamma, const float* __restrict__ beta,
    const float* __restrict__ rm, const float* __restrict__ rv,
    unsigned short* __restrict__ wqkv, unsigned short* __restrict__ wrb,
    float* __restrict__ bqkv, float* __restrict__ scale, float* __restrict__ off2)
{
  __shared__ unsigned short tile[64][72];
  const int t = threadIdx.x;
  const int bid = blockIdx.x + blockIdx.y * 64 + blockIdx.z * 512;

  if (bid < 1536) {
    int i = bid * 256 + t;
    if (i < 768 * 512) {
      int o = i >> 9, c = i & 511;
      float v = (o < 256) ? Wq[o * 512 + c] : (o < 512 ? Wk[(o - 256) * 512 + c] : Wv[(o - 512) * 512 + c]);
      wqkv[i] = f2b(v);
    }
    if (i < 512 * 256) wrb[i] = f2b(Wr[i]);
    if (i < 768) bqkv[i] = (i < 256) ? bq[i] : (i < 512 ? bk[i - 256] : bv[i - 512]);
    if (i < 512) {
      float inv = gamma[i] * rsqrtf(rv[i] + 1e-5f);
      scale[i] = inv;
      off2[i] = (br[i] - rm[i]) * inv + beta[i];
    }
  }

  const int b = blockIdx.z, c0 = blockIdx.y * 64, s0 = blockIdx.x * 64;
  const int r = t >> 2, cc = (t & 3) * 16;
  const float* src = x + ((size_t)b * 512 + c0 + r) * 4096 + s0 + cc;
  #pragma unroll
  for (int j = 0; j < 16; j += 4) {
    float4 v = *(const float4*)(src + j);
    tile[r][cc + j + 0] = f2b(v.x);
    tile[r][cc + j + 1] = f2b(v.y);
    tile[r][cc + j + 2] = f2b(v.z);
    tile[r][cc + j + 3] = f2b(v.w);
  }
  __syncthreads();
  unsigned short* dst = xt + ((size_t)b * 4096 + s0 + r) * 512 + c0 + cc;
  bf16x8 o0, o1;
  #pragma unroll
  for (int j = 0; j < 8; ++j) { o0[j] = tile[cc + j][r]; o1[j] = tile[cc + 8 + j][r]; }
  *(bf16x8*)(dst) = o0;
  *(bf16x8*)(dst + 8) = o1;
}

// ---------------- G1: QKV GEMM, 256x256 tile, BK=64, 8-phase schedule, 8 waves ----------------
// Tiles: M=768 (3), N=4096 (16), per batch. LDS 128 KiB double-buffered.
// Per K-tile: 4 phases; next tile's 8 GL16 issued in phases 0-1; vmcnt(4) counted wait
// (drain 0 only on last tile); per phase: ds_read quadrant -> bar -> lgkm0 -> setprio MFMA -> bar.
__global__ __launch_bounds__(512, 2) void k_qkv(
    const unsigned short* __restrict__ xt, const unsigned short* __restrict__ wqkv,
    const float* __restrict__ bqkv, unsigned short* __restrict__ qkv)
{
  __shared__ unsigned short Ab[2][16384];  // [buf][256 rows][64 k]
  __shared__ unsigned short Bb[2][16384];
  const int b = blockIdx.z, o0 = blockIdx.y * 256, s0 = blockIdx.x * 256;
  const int t = threadIdx.x, w = t >> 6, l = t & 63;
  const int wm = w >> 2, wn = w & 3, lr = l & 15;
  const int lkE = (l >> 4) * 8;
  const int swE = (lr & 7) * 8;
  const int cp = (t & 7) ^ ((t >> 3) & 7);   // staging source-piece pre-swizzle

  // thread stages row (t>>3) of each 64-row chunk, 16B piece cp (pre-swizzled)
  const unsigned short* Ag = wqkv + (size_t)(o0 + (t >> 3)) * 512 + cp * 8;
  const unsigned short* Bg = xt + ((size_t)b * 4096 + s0 + (t >> 3)) * 512 + cp * 8;

  const f32x4 z = {0.f, 0.f, 0.f, 0.f};
  f32x4 acc[8][4];
  #pragma unroll
  for (int i = 0; i < 8; ++i)
    #pragma unroll
    for (int j = 0; j < 4; ++j) acc[i][j] = z;

  // stage chunk-pair ph (chunks 2ph, 2ph+1 of A and B) of K-tile kt into buffer bn
#define STG4(bn, kt, ph) do { \
    GL16(Ag + (kt) * 64 + (size_t)(2 * (ph) + 0) * 64 * 512, (char*)&Ab[bn][0] + (2 * (ph) + 0) * 8192 + t * 16); \
    GL16(Ag + (kt) * 64 + (size_t)(2 * (ph) + 1) * 64 * 512, (char*)&Ab[bn][0] + (2 * (ph) + 1) * 8192 + t * 16); \
    GL16(Bg + (kt) * 64 + (size_t)(2 * (ph) + 0) * 64 * 512, (char*)&Bb[bn][0] + (2 * (ph) + 0) * 8192 + t * 16); \
    GL16(Bg + (kt) * 64 + (size_t)(2 * (ph) + 1) * 64 * 512, (char*)&Bb[bn][0] + (2 * (ph) + 1) * 8192 + t * 16); \
  } while (0)

  bf16x8 af[2][4];   // A-frags cached across the nh pair of phases
  // quadrant (mh, nh): A rows wm*128+(mh*4+mi4)*16+lr, B rows wn*64+(nh*2+ni2)*16+lr
#define PHASE(bn, mh, nh, LOADA) do { \
    bf16x8 bfr[2][2]; \
    _Pragma("unroll") \
    for (int kc = 0; kc < 2; ++kc) { \
      const int kidx = (kc * 32 + lkE) ^ swE; \
      if (LOADA) { \
        _Pragma("unroll") \
        for (int mi4 = 0; mi4 < 4; ++mi4) \
          af[kc][mi4] = *(const bf16x8*)(&Ab[bn][(wm * 128 + ((mh) * 4 + mi4) * 16 + lr) * 64 + kidx]); \
      } \
      _Pragma("unroll") \
      for (int ni2 = 0; ni2 < 2; ++ni2) \
        bfr[kc][ni2] = *(const bf16x8*)(&Bb[bn][(wn * 64 + ((nh) * 2 + ni2) * 16 + lr) * 64 + kidx]); \
    } \
    WAITLGKM; SCHEDBAR; \
    __builtin_amdgcn_s_setprio(1); \
    _Pragma("unroll") \
    for (int kc = 0; kc < 2; ++kc) \
      _Pragma("unroll") \
      for (int mi4 = 0; mi4 < 4; ++mi4) \
        _Pragma("unroll") \
        for (int ni2 = 0; ni2 < 2; ++ni2) \
          acc[(mh) * 4 + mi4][(nh) * 2 + ni2] = \
            __builtin_amdgcn_mfma_f32_16x16x32_bf16(af[kc][mi4], bfr[kc][ni2], acc[(mh) * 4 + mi4][(nh) * 2 + ni2], 0, 0, 0); \
    __builtin_amdgcn_s_setprio(0); \
  } while (0)

  STG4(0, 0, 0); STG4(0, 0, 1);   // tile 0 fully staged (8 loads)
  #pragma unroll
  for (int kt = 0; kt < 8; ++kt) {
    const int bn = kt & 1;
    // ---- phase 0 (mh=0, nh=0): issue next tile's first chunk-pair, counted wait ----
    if (kt < 7) STG4(bn ^ 1, kt + 1, 0);
    if (kt == 7) { WAITVM(0); } else { WAITVM(4); }
    __builtin_amdgcn_s_barrier(); SCHEDBAR;
    PHASE(bn, 0, 0, 1);
    __builtin_amdgcn_s_barrier(); SCHEDBAR;
    // ---- phase 1 (mh=0, nh=1): issue next tile's second chunk-pair ----
    if (kt < 7) STG4(bn ^ 1, kt + 1, 1);
    PHASE(bn, 0, 1, 0);
    __builtin_amdgcn_s_barrier(); SCHEDBAR;
    // ---- phase 2 (mh=1, nh=0) ----
    PHASE(bn, 1, 0, 1);
    __builtin_amdgcn_s_barrier(); SCHEDBAR;
    // ---- phase 3 (mh=1, nh=1) ----
    PHASE(bn, 1, 1, 0);
    __builtin_amdgcn_s_barrier(); SCHEDBAR;
  }

  // epilogue: D row = o (lane>>4)*4+reg, col = s (lane&15); store bf16 to q/k/v
  #pragma unroll
  for (int mi = 0; mi < 8; ++mi) {
    #pragma unroll
    for (int reg = 0; reg < 4; ++reg) {
      const int o = o0 + wm * 128 + mi * 16 + (l >> 4) * 4 + reg;
      const float bias = bqkv[o];
      const size_t base = (size_t)(o >> 8) * 16777216ull + ((size_t)b * 256 + (o & 255)) * 4096;
      #pragma unroll
      for (int ni = 0; ni < 4; ++ni) {
        const int s = s0 + wn * 64 + ni * 16 + lr;
        qkv[base + s] = f2b(acc[mi][ni][reg] + bias);
      }
    }
  }
#undef STG4
#undef PHASE
}

// ---------------- G2: per-group attention ----------------
__global__ __launch_bounds__(256) void k_attn(const unsigned short* __restrict__ qkv,
                                              unsigned short* __restrict__ yout)
{
  __shared__ unsigned short Vt[64][80];
  __shared__ unsigned short P[4][16][80];
  const int g = blockIdx.x;
  const unsigned short* qg = qkv + (size_t)g * 4096;
  const unsigned short* kg = qkv + 16777216ull + (size_t)g * 4096;
  const unsigned short* vg = qkv + 33554432ull + (size_t)g * 4096;
  const int t = threadIdx.x, w = t >> 6, l = t & 63;
  const int lr = l & 15, lk = (l >> 4) * 8;

  {
    const int j = t >> 2, c0 = (t & 3) * 16;
    bf16x8 a = *(const bf16x8*)(vg + j * 64 + c0);
    bf16x8 bb = *(const bf16x8*)(vg + j * 64 + c0 + 8);
    #pragma unroll
    for (int jj = 0; jj < 8; ++jj) { Vt[c0 + jj][j] = a[jj]; Vt[c0 + 8 + jj][j] = bb[jj]; }
  }

  const f32x4 z = {0.f, 0.f, 0.f, 0.f};
  bf16x8 qf[2];
  #pragma unroll
  for (int kc = 0; kc < 2; ++kc) qf[kc] = *(const bf16x8*)(qg + (w * 16 + lr) * 64 + kc * 32 + lk);
  f32x4 accS[4] = {z, z, z, z};
  __builtin_amdgcn_s_setprio(1);
  #pragma unroll
  for (int jt = 0; jt < 4; ++jt)
    #pragma unroll
    for (int kc = 0; kc < 2; ++kc) {
      bf16x8 kf = *(const bf16x8*)(kg + (jt * 16 + lr) * 64 + kc * 32 + lk);
      accS[jt] = __builtin_amdgcn_mfma_f32_16x16x32_bf16(qf[kc], kf, accS[jt], 0, 0, 0);
    }
  __builtin_amdgcn_s_setprio(0);

  #pragma unroll
  for (int reg = 0; reg < 4; ++reg) {
    float mx = fmaxf(fmaxf(accS[0][reg], accS[1][reg]), fmaxf(accS[2][reg], accS[3][reg]));
    #pragma unroll
    for (int m = 1; m < 16; m <<= 1) mx = fmaxf(mx, __shfl_xor(mx, m, 64));
    float e0 = __expf(accS[0][reg] - mx), e1 = __expf(accS[1][reg] - mx);
    float e2 = __expf(accS[2][reg] - mx), e3 = __expf(accS[3][reg] - mx);
    float sm = e0 + e1 + e2 + e3;
    #pragma unroll
    for (int m = 1; m < 16; m <<= 1) sm += __shfl_xor(sm, m, 64);
    const float rs = 1.f / sm;
    const int row = (l >> 4) * 4 + reg;
    P[w][row][0 * 16 + lr] = f2b(e0 * rs);
    P[w][row][1 * 16 + lr] = f2b(e1 * rs);
    P[w][row][2 * 16 + lr] = f2b(e2 * rs);
    P[w][row][3 * 16 + lr] = f2b(e3 * rs);
  }
  __syncthreads();

  bf16x8 pf[2];
  #pragma unroll
  for (int kc = 0; kc < 2; ++kc) pf[kc] = *(const bf16x8*)(&P[w][lr][kc * 32 + lk]);
  f32x4 accY[4] = {z, z, z, z};
  __builtin_amdgcn_s_setprio(1);
  #pragma unroll
  for (int nt = 0; nt < 4; ++nt)
    #pragma unroll
    for (int kc = 0; kc < 2; ++kc) {
      bf16x8 vf = *(const bf16x8*)(&Vt[nt * 16 + lr][kc * 32 + lk]);
      accY[nt] = __builtin_amdgcn_mfma_f32_16x16x32_bf16(pf[kc], vf, accY[nt], 0, 0, 0);
    }
  __builtin_amdgcn_s_setprio(0);

  unsigned short* yg = yout + (size_t)g * 4096;
  #pragma unroll
  for (int nt = 0; nt < 4; ++nt)
    #pragma unroll
    for (int reg = 0; reg < 4; ++reg) {
      const int i = w * 16 + (l >> 4) * 4 + reg;
      yg[i * 64 + nt * 16 + lr] = f2b(accY[nt][reg]);
    }
}

// ---------------- G2b: y [B][CR][S] -> yt [B][S][CR] ----------------
__global__ __launch_bounds__(256) void k_yt(const unsigned short* __restrict__ y, unsigned short* __restrict__ yt)
{
  __shared__ unsigned short tile[64][72];
  const int b = blockIdx.z, cr0 = blockIdx.y * 64, s0 = blockIdx.x * 64;
  const int t = threadIdx.x, r = t >> 2, c0 = (t & 3) * 16;
  const unsigned short* src = y + ((size_t)b * 256 + cr0 + r) * 4096 + s0 + c0;
  bf16x8 a = *(const bf16x8*)(src);
  bf16x8 bb = *(const bf16x8*)(src + 8);
  #pragma unroll
  for (int j = 0; j < 8; ++j) { tile[r][c0 + j] = a[j]; tile[r][c0 + 8 + j] = bb[j]; }
  __syncthreads();
  unsigned short* dst = yt + ((size_t)b * 4096 + s0 + r) * 256 + cr0 + c0;
  bf16x8 o0, o1;
  #pragma unroll
  for (int j = 0; j < 8; ++j) { o0[j] = tile[c0 + j][r]; o1[j] = tile[c0 + 8 + j][r]; }
  *(bf16x8*)(dst) = o0;
  *(bf16x8*)(dst + 8) = o1;
}

// ---------------- G3: recon GEMM + BN + residual, 128x128, BK=64, ring-2, swizzled LDS ----------------
__global__ __launch_bounds__(256) void k_recon(
    const unsigned short* __restrict__ yt, const unsigned short* __restrict__ wrb,
    const float* __restrict__ scale, const float* __restrict__ off2,
    const float* __restrict__ x, float* __restrict__ out)
{
  __shared__ unsigned short lds[2][2][8192];  // 64 KB
  const int b = blockIdx.z, o0 = blockIdx.y * 128, s0 = blockIdx.x * 128;
  const int t = threadIdx.x, w = t >> 6, l = t & 63;
  const int wm = w >> 1, wn = w & 1, lr = l & 15;
  const int lkE = (l >> 4) * 8;
  const int swE = (lr & 7) * 8;
  const int cp = (t & 7) ^ ((t >> 3) & 7);

  const unsigned short* Ag = wrb + (size_t)(o0 + (t >> 3)) * 256 + cp * 8;
  const unsigned short* Bg = yt + ((size_t)b * 4096 + s0 + (t >> 3)) * 256 + cp * 8;

  const f32x4 z = {0.f, 0.f, 0.f, 0.f};
  f32x4 acc[4][4];
  #pragma unroll
  for (int i = 0; i < 4; ++i)
    #pragma unroll
    for (int j = 0; j < 4; ++j) acc[i][j] = z;

#define STG_R(st, kt) do { \
    _Pragma("unroll") \
    for (int j = 0; j < 4; ++j) { \
      GL16(Ag + (kt) * 64 + j * 32 * 256, (char*)&lds[st][0][0] + j * 4096 + t * 16); \
      GL16(Bg + (kt) * 64 + j * 32 * 256, (char*)&lds[st][1][0] + j * 4096 + t * 16); \
    } \
  } while (0)

#define CMP_R(st) do { \
    const unsigned short* A  = &lds[st][0][0]; \
    const unsigned short* Bl = &lds[st][1][0]; \
    _Pragma("unroll") \
    for (int kc = 0; kc < 2; ++kc) { \
      const int kidx = (kc * 32 + lkE) ^ swE; \
      bf16x8 af[4], bfr[4]; \
      _Pragma("unroll") \
      for (int mi = 0; mi < 4; ++mi) af[mi] = *(const bf16x8*)(A + (wm * 64 + mi * 16 + lr) * 64 + kidx); \
      _Pragma("unroll") \
      for (int ni = 0; ni < 4; ++ni) bfr[ni] = *(const bf16x8*)(Bl + (wn * 64 + ni * 16 + lr) * 64 + kidx); \
      _Pragma("unroll") \
      for (int mi = 0; mi < 4; ++mi) \
        _Pragma("unroll") \
        for (int ni = 0; ni < 4; ++ni) \
          acc[mi][ni] = __builtin_amdgcn_mfma_f32_16x16x32_bf16(af[mi], bfr[ni], acc[mi][ni], 0, 0, 0); \
    } \
    WAITLGKM; SCHEDBAR; \
  } while (0)

  STG_R(0, 0); STG_R(1, 1);
  #pragma unroll
  for (int kt = 0; kt < 3; ++kt) {
    WAITVM(8);
    __builtin_amdgcn_s_barrier(); SCHEDBAR;
    CMP_R(kt & 1);
    __builtin_amdgcn_s_barrier(); SCHEDBAR;
    if (kt + 2 < 4) STG_R(kt & 1, kt + 2);
  }
  WAITVM(0);
  __builtin_amdgcn_s_barrier(); SCHEDBAR;
  CMP_R(1);   // kt=3

  // epilogue: out = acc*scale[o] + off2[o] + x
  #pragma unroll
  for (int mi = 0; mi < 4; ++mi) {
    #pragma unroll
    for (int reg = 0; reg < 4; ++reg) {
      const int o = o0 + wm * 64 + mi * 16 + (l >> 4) * 4 + reg;
      const float sc = scale[o], of = off2[o];
      const size_t base = ((size_t)b * 512 + o) * 4096;
      #pragma unroll
      for (int ni = 0; ni < 4; ++ni) {
        const int s = s0 + wn * 64 + ni * 16 + lr;
        const size_t idx = base + s;
        out[idx] = acc[mi][ni][reg] * sc + of + x[idx];
      }
    }
  }
#undef STG_R
#undef CMP_R
}

extern "C" void kernel_launch(void* const* d_in, const int* in_sizes, int n_in,
                              void* d_out, int out_size, void* d_ws, size_t ws_size,
                              hipStream_t stream)
{
  const float* x     = (const float*)d_in[0];
  const float* Wq    = (const float*)d_in[1];
  const float* bq    = (const float*)d_in[2];
  const float* Wk    = (const float*)d_in[3];
  const float* bk    = (const float*)d_in[4];
  const float* Wv    = (const float*)d_in[5];
  const float* bv    = (const float*)d_in[6];
  const float* Wr    = (const float*)d_in[7];
  const float* br    = (const float*)d_in[8];
  const float* gamma = (const float*)d_in[9];
  const float* beta  = (const float*)d_in[10];
  const float* rm    = (const float*)d_in[11];
  const float* rv    = (const float*)d_in[12];

  char* ws = (char*)d_ws;
  unsigned short* wqkv  = (unsigned short*)(ws + OFF_WQKV);
  unsigned short* wrb   = (unsigned short*)(ws + OFF_WR);
  float* bqkv  = (float*)(ws + OFF_BQKV);
  float* scale = (float*)(ws + OFF_SCALE);
  float* off2  = (float*)(ws + OFF_OFF2);
  unsigned short* xt  = (unsigned short*)(ws + OFF_XT);
  unsigned short* yt  = (unsigned short*)(ws + OFF_YT);
  unsigned short* yb  = (unsigned short*)(ws + OFF_Y);
  unsigned short* qkv = (unsigned short*)(ws + OFF_Q);
  float* out = (float*)d_out;

  hipLaunchKernelGGL(k_xt, dim3(64, 8, 16), dim3(256), 0, stream,
                     x, xt, Wq, bq, Wk, bk, Wv, bv, Wr, br, gamma, beta, rm, rv,
                     wqkv, wrb, bqkv, scale, off2);
  hipLaunchKernelGGL(k_qkv, dim3(16, 3, 16), dim3(512), 0, stream, xt, wqkv, bqkv, qkv);
  hipLaunchKernelGGL(k_attn, dim3(4096), dim3(256), 0, stream, qkv, yb);
  hipLaunchKernelGGL(k_yt, dim3(64, 4, 16), dim3(256), 0, stream, yb, yt);
  hipLaunchKernelGGL(k_recon, dim3(32, 4, 16), dim3(256), 0, stream, yt, wrb, scale, off2, x, out);
}

// Round 7
// 214.450 us; speedup vs baseline: 1.0250x; 1.0250x over previous
//
#include <hip/hip_runtime.h>

// types
typedef __attribute__((ext_vector_type(8))) short bf16x8;
typedef __attribute__((ext_vector_type(4))) float f32x4;

#define DEVI static __device__ __forceinline__

DEVI unsigned short f2b(float f) {
  union { float f; unsigned u; } v; v.f = f;
  unsigned r = v.u + 0x7fffu + ((v.u >> 16) & 1u);
  return (unsigned short)(r >> 16);
}

typedef const __attribute__((address_space(1))) void* gas1_t;
typedef __attribute__((address_space(3))) void* las3_t;
#define GL16(g, l) __builtin_amdgcn_global_load_lds((gas1_t)(g), (las3_t)(l), 16, 0, 0)

#define WAITVM(N) asm volatile("s_waitcnt vmcnt(" #N ")" ::: "memory")
#define WAITLGKM  asm volatile("s_waitcnt lgkmcnt(0)" ::: "memory")
#define SCHEDBAR  __builtin_amdgcn_sched_barrier(0)

// ---- workspace layout (bytes) ----
#define OFF_WQKV  0ull          // 768*512*2
#define OFF_WR    786432ull     // 512*256*2
#define OFF_BQKV  1048576ull
#define OFF_SCALE 1051648ull
#define OFF_OFF2  1053696ull
#define OFF_XT    2097152ull    // xt bf16 [16][4096][512] = 64 MiB
#define OFF_YT    2097152ull    // yt bf16 [16][4096][256] = 32 MiB (reuses xt after qkv)
#define OFF_Y     35651584ull   // y  bf16 [16][256][4096] = 32 MiB
#define OFF_Q     69206016ull   // qkv bf16: q,k,v each 16777216 u16

// ---------------- P1: x [B][C][S] f32 -> xt [B][S][C] bf16  (+ fused weight prep) ----------------
__global__ __launch_bounds__(256) void k_xt(
    const float* __restrict__ x, unsigned short* __restrict__ xt,
    const float* __restrict__ Wq, const float* __restrict__ bq,
    const float* __restrict__ Wk, const float* __restrict__ bk,
    const float* __restrict__ Wv, const float* __restrict__ bv,
    const float* __restrict__ Wr, const float* __restrict__ br,
    const float* __restrict__ gamma, const float* __restrict__ beta,
    const float* __restrict__ rm, const float* __restrict__ rv,
    unsigned short* __restrict__ wqkv, unsigned short* __restrict__ wrb,
    float* __restrict__ bqkv, float* __restrict__ scale, float* __restrict__ off2)
{
  __shared__ unsigned short tile[64][72];
  const int t = threadIdx.x;
  const int bid = blockIdx.x + blockIdx.y * 64 + blockIdx.z * 512;

  if (bid < 1536) {
    int i = bid * 256 + t;
    if (i < 768 * 512) {
      int o = i >> 9, c = i & 511;
      float v = (o < 256) ? Wq[o * 512 + c] : (o < 512 ? Wk[(o - 256) * 512 + c] : Wv[(o - 512) * 512 + c]);
      wqkv[i] = f2b(v);
    }
    if (i < 512 * 256) wrb[i] = f2b(Wr[i]);
    if (i < 768) bqkv[i] = (i < 256) ? bq[i] : (i < 512 ? bk[i - 256] : bv[i - 512]);
    if (i < 512) {
      float inv = gamma[i] * rsqrtf(rv[i] + 1e-5f);
      scale[i] = inv;
      off2[i] = (br[i] - rm[i]) * inv + beta[i];
    }
  }

  const int b = blockIdx.z, c0 = blockIdx.y * 64, s0 = blockIdx.x * 64;
  const int r = t >> 2, cc = (t & 3) * 16;
  const float* src = x + ((size_t)b * 512 + c0 + r) * 4096 + s0 + cc;
  #pragma unroll
  for (int j = 0; j < 16; j += 4) {
    float4 v = *(const float4*)(src + j);
    tile[r][cc + j + 0] = f2b(v.x);
    tile[r][cc + j + 1] = f2b(v.y);
    tile[r][cc + j + 2] = f2b(v.z);
    tile[r][cc + j + 3] = f2b(v.w);
  }
  __syncthreads();
  unsigned short* dst = xt + ((size_t)b * 4096 + s0 + r) * 512 + c0 + cc;
  bf16x8 o0, o1;
  #pragma unroll
  for (int j = 0; j < 8; ++j) { o0[j] = tile[cc + j][r]; o1[j] = tile[cc + 8 + j][r]; }
  *(bf16x8*)(dst) = o0;
  *(bf16x8*)(dst + 8) = o1;
}

// ---------------- G1: QKV GEMM, 256x256, BK=64, corrected 8-phase (reads BEFORE barrier) ----------------
// 8 waves (2M x 4N), per-wave 128x64 output. LDS 128 KiB (2 x [256][64] x A,B).
// Per tile: 4 phases; each phase: {ds_read quadrant || 2xGL16 of tile kt+1 -> barrier ->
// lgkmcnt(0) -> setprio(1) 16 MFMA setprio(0) -> barrier}. Phase 0 gates tile data with
// vmcnt(2) + barrier BEFORE its reads. 1-tile-ahead prefetch into the other buffer.
__global__ __launch_bounds__(512, 2) void k_qkv(
    const unsigned short* __restrict__ xt, const unsigned short* __restrict__ wqkv,
    const float* __restrict__ bqkv, unsigned short* __restrict__ qkv)
{
  __shared__ unsigned short Ab[2][16384];  // [buf][256 rows][64 k]
  __shared__ unsigned short Bb[2][16384];
  const int b = blockIdx.z, o0 = blockIdx.y * 256, s0 = blockIdx.x * 256;
  const int t = threadIdx.x, w = t >> 6, l = t & 63;
  const int wm = w >> 2, wn = w & 3, lr = l & 15;
  const int lkE = (l >> 4) * 8;
  const int swE = (lr & 7) * 8;
  const int cp = (t & 7) ^ ((t >> 3) & 7);   // staging source-piece pre-swizzle

  const unsigned short* Ag = wqkv + (size_t)(o0 + (t >> 3)) * 512 + cp * 8;
  const unsigned short* Bg = xt + ((size_t)b * 4096 + s0 + (t >> 3)) * 512 + cp * 8;

  const f32x4 z = {0.f, 0.f, 0.f, 0.f};
  f32x4 acc[8][4];
  #pragma unroll
  for (int i = 0; i < 8; ++i)
    #pragma unroll
    for (int j = 0; j < 4; ++j) acc[i][j] = z;

  // stage unit h: h=0 -> A chunks 0,1; h=1 -> A chunks 2,3; h=2 -> B chunks 0,1; h=3 -> B chunks 2,3
#define STG2(bn, kt, h) do { \
    const int c0_ = ((h) & 1) * 2, c1_ = c0_ + 1; \
    if ((h) < 2) { \
      GL16(Ag + (kt) * 64 + (size_t)c0_ * 64 * 512, (char*)&Ab[bn][0] + c0_ * 8192 + t * 16); \
      GL16(Ag + (kt) * 64 + (size_t)c1_ * 64 * 512, (char*)&Ab[bn][0] + c1_ * 8192 + t * 16); \
    } else { \
      GL16(Bg + (kt) * 64 + (size_t)c0_ * 64 * 512, (char*)&Bb[bn][0] + c0_ * 8192 + t * 16); \
      GL16(Bg + (kt) * 64 + (size_t)c1_ * 64 * 512, (char*)&Bb[bn][0] + c1_ * 8192 + t * 16); \
    } \
  } while (0)

  bf16x8 af[2][4];   // A-frags persist across the nh pair of phases

#define READ_A(bn, mh) do { \
    _Pragma("unroll") \
    for (int kc = 0; kc < 2; ++kc) { \
      const int kidx = (kc * 32 + lkE) ^ swE; \
      _Pragma("unroll") \
      for (int mi4 = 0; mi4 < 4; ++mi4) \
        af[kc][mi4] = *(const bf16x8*)(&Ab[bn][(wm * 128 + ((mh) * 4 + mi4) * 16 + lr) * 64 + kidx]); \
    } \
  } while (0)

#define READ_B(bn, nh, bfr) do { \
    _Pragma("unroll") \
    for (int kc = 0; kc < 2; ++kc) { \
      const int kidx = (kc * 32 + lkE) ^ swE; \
      _Pragma("unroll") \
      for (int ni2 = 0; ni2 < 2; ++ni2) \
        bfr[kc][ni2] = *(const bf16x8*)(&Bb[bn][(wn * 64 + ((nh) * 2 + ni2) * 16 + lr) * 64 + kidx]); \
    } \
  } while (0)

#define MFMA_Q(mh, nh, bfr) do { \
    WAITLGKM; SCHEDBAR; \
    __builtin_amdgcn_s_setprio(1); \
    _Pragma("unroll") \
    for (int kc = 0; kc < 2; ++kc) \
      _Pragma("unroll") \
      for (int mi4 = 0; mi4 < 4; ++mi4) \
        _Pragma("unroll") \
        for (int ni2 = 0; ni2 < 2; ++ni2) \
          acc[(mh) * 4 + mi4][(nh) * 2 + ni2] = \
            __builtin_amdgcn_mfma_f32_16x16x32_bf16(af[kc][mi4], bfr[kc][ni2], acc[(mh) * 4 + mi4][(nh) * 2 + ni2], 0, 0, 0); \
    __builtin_amdgcn_s_setprio(0); \
  } while (0)

  // prologue: fully stage tile 0
  STG2(0, 0, 0); STG2(0, 0, 1); STG2(0, 0, 2); STG2(0, 0, 3);

  #pragma unroll
  for (int kt = 0; kt < 8; ++kt) {
    const int bn = kt & 1;
    bf16x8 bfr[2][2];
    // ---- phase 0 (mh=0,nh=0): gate tile kt, reads after publishing barrier ----
    if (kt < 7) STG2(bn ^ 1, kt + 1, 0);
    if (kt == 7) { WAITVM(0); } else { WAITVM(2); }
    __builtin_amdgcn_s_barrier(); SCHEDBAR;
    READ_A(bn, 0); READ_B(bn, 0, bfr); SCHEDBAR;
    MFMA_Q(0, 0, bfr);
    __builtin_amdgcn_s_barrier(); SCHEDBAR;
    // ---- phase 1 (mh=0,nh=1): reads PRE-barrier ----
    READ_B(bn, 1, bfr); SCHEDBAR;
    if (kt < 7) STG2(bn ^ 1, kt + 1, 1);
    __builtin_amdgcn_s_barrier(); SCHEDBAR;
    MFMA_Q(0, 1, bfr);
    __builtin_amdgcn_s_barrier(); SCHEDBAR;
    // ---- phase 2 (mh=1,nh=0) ----
    READ_A(bn, 1); READ_B(bn, 0, bfr); SCHEDBAR;
    if (kt < 7) STG2(bn ^ 1, kt + 1, 2);
    __builtin_amdgcn_s_barrier(); SCHEDBAR;
    MFMA_Q(1, 0, bfr);
    __builtin_amdgcn_s_barrier(); SCHEDBAR;
    // ---- phase 3 (mh=1,nh=1) ----
    READ_B(bn, 1, bfr); SCHEDBAR;
    if (kt < 7) STG2(bn ^ 1, kt + 1, 3);
    __builtin_amdgcn_s_barrier(); SCHEDBAR;
    MFMA_Q(1, 1, bfr);
    __builtin_amdgcn_s_barrier(); SCHEDBAR;
  }

  // epilogue: D row = o (lane>>4)*4+reg, col = s (lane&15); store bf16 to q/k/v
  #pragma unroll
  for (int mi = 0; mi < 8; ++mi) {
    #pragma unroll
    for (int reg = 0; reg < 4; ++reg) {
      const int o = o0 + wm * 128 + mi * 16 + (l >> 4) * 4 + reg;
      const float bias = bqkv[o];
      const size_t base = (size_t)(o >> 8) * 16777216ull + ((size_t)b * 256 + (o & 255)) * 4096;
      #pragma unroll
      for (int ni = 0; ni < 4; ++ni) {
        const int s = s0 + wn * 64 + ni * 16 + lr;
        qkv[base + s] = f2b(acc[mi][ni][reg] + bias);
      }
    }
  }
#undef STG2
#undef READ_A
#undef READ_B
#undef MFMA_Q
}

// ---------------- G2: per-group attention ----------------
__global__ __launch_bounds__(256) void k_attn(const unsigned short* __restrict__ qkv,
                                              unsigned short* __restrict__ yout)
{
  __shared__ unsigned short Vt[64][80];
  __shared__ unsigned short P[4][16][80];
  const int g = blockIdx.x;
  const unsigned short* qg = qkv + (size_t)g * 4096;
  const unsigned short* kg = qkv + 16777216ull + (size_t)g * 4096;
  const unsigned short* vg = qkv + 33554432ull + (size_t)g * 4096;
  const int t = threadIdx.x, w = t >> 6, l = t & 63;
  const int lr = l & 15, lk = (l >> 4) * 8;

  {
    const int j = t >> 2, c0 = (t & 3) * 16;
    bf16x8 a = *(const bf16x8*)(vg + j * 64 + c0);
    bf16x8 bb = *(const bf16x8*)(vg + j * 64 + c0 + 8);
    #pragma unroll
    for (int jj = 0; jj < 8; ++jj) { Vt[c0 + jj][j] = a[jj]; Vt[c0 + 8 + jj][j] = bb[jj]; }
  }

  const f32x4 z = {0.f, 0.f, 0.f, 0.f};
  bf16x8 qf[2];
  #pragma unroll
  for (int kc = 0; kc < 2; ++kc) qf[kc] = *(const bf16x8*)(qg + (w * 16 + lr) * 64 + kc * 32 + lk);
  f32x4 accS[4] = {z, z, z, z};
  __builtin_amdgcn_s_setprio(1);
  #pragma unroll
  for (int jt = 0; jt < 4; ++jt)
    #pragma unroll
    for (int kc = 0; kc < 2; ++kc) {
      bf16x8 kf = *(const bf16x8*)(kg + (jt * 16 + lr) * 64 + kc * 32 + lk);
      accS[jt] = __builtin_amdgcn_mfma_f32_16x16x32_bf16(qf[kc], kf, accS[jt], 0, 0, 0);
    }
  __builtin_amdgcn_s_setprio(0);

  #pragma unroll
  for (int reg = 0; reg < 4; ++reg) {
    float mx = fmaxf(fmaxf(accS[0][reg], accS[1][reg]), fmaxf(accS[2][reg], accS[3][reg]));
    #pragma unroll
    for (int m = 1; m < 16; m <<= 1) mx = fmaxf(mx, __shfl_xor(mx, m, 64));
    float e0 = __expf(accS[0][reg] - mx), e1 = __expf(accS[1][reg] - mx);
    float e2 = __expf(accS[2][reg] - mx), e3 = __expf(accS[3][reg] - mx);
    float sm = e0 + e1 + e2 + e3;
    #pragma unroll
    for (int m = 1; m < 16; m <<= 1) sm += __shfl_xor(sm, m, 64);
    const float rs = 1.f / sm;
    const int row = (l >> 4) * 4 + reg;
    P[w][row][0 * 16 + lr] = f2b(e0 * rs);
    P[w][row][1 * 16 + lr] = f2b(e1 * rs);
    P[w][row][2 * 16 + lr] = f2b(e2 * rs);
    P[w][row][3 * 16 + lr] = f2b(e3 * rs);
  }
  __syncthreads();

  bf16x8 pf[2];
  #pragma unroll
  for (int kc = 0; kc < 2; ++kc) pf[kc] = *(const bf16x8*)(&P[w][lr][kc * 32 + lk]);
  f32x4 accY[4] = {z, z, z, z};
  __builtin_amdgcn_s_setprio(1);
  #pragma unroll
  for (int nt = 0; nt < 4; ++nt)
    #pragma unroll
    for (int kc = 0; kc < 2; ++kc) {
      bf16x8 vf = *(const bf16x8*)(&Vt[nt * 16 + lr][kc * 32 + lk]);
      accY[nt] = __builtin_amdgcn_mfma_f32_16x16x32_bf16(pf[kc], vf, accY[nt], 0, 0, 0);
    }
  __builtin_amdgcn_s_setprio(0);

  unsigned short* yg = yout + (size_t)g * 4096;
  #pragma unroll
  for (int nt = 0; nt < 4; ++nt)
    #pragma unroll
    for (int reg = 0; reg < 4; ++reg) {
      const int i = w * 16 + (l >> 4) * 4 + reg;
      yg[i * 64 + nt * 16 + lr] = f2b(accY[nt][reg]);
    }
}

// ---------------- G2b: y [B][CR][S] -> yt [B][S][CR] ----------------
__global__ __launch_bounds__(256) void k_yt(const unsigned short* __restrict__ y, unsigned short* __restrict__ yt)
{
  __shared__ unsigned short tile[64][72];
  const int b = blockIdx.z, cr0 = blockIdx.y * 64, s0 = blockIdx.x * 64;
  const int t = threadIdx.x, r = t >> 2, c0 = (t & 3) * 16;
  const unsigned short* src = y + ((size_t)b * 256 + cr0 + r) * 4096 + s0 + c0;
  bf16x8 a = *(const bf16x8*)(src);
  bf16x8 bb = *(const bf16x8*)(src + 8);
  #pragma unroll
  for (int j = 0; j < 8; ++j) { tile[r][c0 + j] = a[j]; tile[r][c0 + 8 + j] = bb[j]; }
  __syncthreads();
  unsigned short* dst = yt + ((size_t)b * 4096 + s0 + r) * 256 + cr0 + c0;
  bf16x8 o0, o1;
  #pragma unroll
  for (int j = 0; j < 8; ++j) { o0[j] = tile[c0 + j][r]; o1[j] = tile[c0 + 8 + j][r]; }
  *(bf16x8*)(dst) = o0;
  *(bf16x8*)(dst + 8) = o1;
}

// ---------------- G3: recon GEMM + BN + residual, 128x128, BK=64, ring-2, loads-upfront CMP ----------------
__global__ __launch_bounds__(256) void k_recon(
    const unsigned short* __restrict__ yt, const unsigned short* __restrict__ wrb,
    const float* __restrict__ scale, const float* __restrict__ off2,
    const float* __restrict__ x, float* __restrict__ out)
{
  __shared__ unsigned short lds[2][2][8192];  // 64 KB
  const int b = blockIdx.z, o0 = blockIdx.y * 128, s0 = blockIdx.x * 128;
  const int t = threadIdx.x, w = t >> 6, l = t & 63;
  const int wm = w >> 1, wn = w & 1, lr = l & 15;
  const int lkE = (l >> 4) * 8;
  const int swE = (lr & 7) * 8;
  const int cp = (t & 7) ^ ((t >> 3) & 7);

  const unsigned short* Ag = wrb + (size_t)(o0 + (t >> 3)) * 256 + cp * 8;
  const unsigned short* Bg = yt + ((size_t)b * 4096 + s0 + (t >> 3)) * 256 + cp * 8;

  const f32x4 z = {0.f, 0.f, 0.f, 0.f};
  f32x4 acc[4][4];
  #pragma unroll
  for (int i = 0; i < 4; ++i)
    #pragma unroll
    for (int j = 0; j < 4; ++j) acc[i][j] = z;

#define STG_R(st, kt) do { \
    _Pragma("unroll") \
    for (int j = 0; j < 4; ++j) { \
      GL16(Ag + (kt) * 64 + j * 32 * 256, (char*)&lds[st][0][0] + j * 4096 + t * 16); \
      GL16(Bg + (kt) * 64 + j * 32 * 256, (char*)&lds[st][1][0] + j * 4096 + t * 16); \
    } \
  } while (0)

#define CMP_R(st) do { \
    const unsigned short* A  = &lds[st][0][0]; \
    const unsigned short* Bl = &lds[st][1][0]; \
    bf16x8 af[2][4], bfr[2][4]; \
    _Pragma("unroll") \
    for (int kc = 0; kc < 2; ++kc) { \
      const int kidx = (kc * 32 + lkE) ^ swE; \
      _Pragma("unroll") \
      for (int mi = 0; mi < 4; ++mi) af[kc][mi] = *(const bf16x8*)(A + (wm * 64 + mi * 16 + lr) * 64 + kidx); \
      _Pragma("unroll") \
      for (int ni = 0; ni < 4; ++ni) bfr[kc][ni] = *(const bf16x8*)(Bl + (wn * 64 + ni * 16 + lr) * 64 + kidx); \
    } \
    _Pragma("unroll") \
    for (int kc = 0; kc < 2; ++kc) \
      _Pragma("unroll") \
      for (int mi = 0; mi < 4; ++mi) \
        _Pragma("unroll") \
        for (int ni = 0; ni < 4; ++ni) \
          acc[mi][ni] = __builtin_amdgcn_mfma_f32_16x16x32_bf16(af[kc][mi], bfr[kc][ni], acc[mi][ni], 0, 0, 0); \
  } while (0)

  STG_R(0, 0); STG_R(1, 1);
  #pragma unroll
  for (int kt = 0; kt < 3; ++kt) {
    WAITVM(8);
    __builtin_amdgcn_s_barrier(); SCHEDBAR;
    CMP_R(kt & 1);
    __builtin_amdgcn_s_barrier(); SCHEDBAR;
    if (kt + 2 < 4) STG_R(kt & 1, kt + 2);
  }
  WAITVM(0);
  __builtin_amdgcn_s_barrier(); SCHEDBAR;
  CMP_R(1);   // kt=3

  // epilogue: out = acc*scale[o] + off2[o] + x
  #pragma unroll
  for (int mi = 0; mi < 4; ++mi) {
    #pragma unroll
    for (int reg = 0; reg < 4; ++reg) {
      const int o = o0 + wm * 64 + mi * 16 + (l >> 4) * 4 + reg;
      const float sc = scale[o], of = off2[o];
      const size_t base = ((size_t)b * 512 + o) * 4096;
      #pragma unroll
      for (int ni = 0; ni < 4; ++ni) {
        const int s = s0 + wn * 64 + ni * 16 + lr;
        const size_t idx = base + s;
        out[idx] = acc[mi][ni][reg] * sc + of + x[idx];
      }
    }
  }
#undef STG_R
#undef CMP_R
}

extern "C" void kernel_launch(void* const* d_in, const int* in_sizes, int n_in,
                              void* d_out, int out_size, void* d_ws, size_t ws_size,
                              hipStream_t stream)
{
  const float* x     = (const float*)d_in[0];
  const float* Wq    = (const float*)d_in[1];
  const float* bq    = (const float*)d_in[2];
  const float* Wk    = (const float*)d_in[3];
  const float* bk    = (const float*)d_in[4];
  const float* Wv    = (const float*)d_in[5];
  const float* bv    = (const float*)d_in[6];
  const float* Wr    = (const float*)d_in[7];
  const float* br    = (const float*)d_in[8];
  const float* gamma = (const float*)d_in[9];
  const float* beta  = (const float*)d_in[10];
  const float* rm    = (const float*)d_in[11];
  const float* rv    = (const float*)d_in[12];

  char* ws = (char*)d_ws;
  unsigned short* wqkv  = (unsigned short*)(ws + OFF_WQKV);
  unsigned short* wrb   = (unsigned short*)(ws + OFF_WR);
  float* bqkv  = (float*)(ws + OFF_BQKV);
  float* scale = (float*)(ws + OFF_SCALE);
  float* off2  = (float*)(ws + OFF_OFF2);
  unsigned short* xt  = (unsigned short*)(ws + OFF_XT);
  unsigned short* yt  = (unsigned short*)(ws + OFF_YT);
  unsigned short* yb  = (unsigned short*)(ws + OFF_Y);
  unsigned short* qkv = (unsigned short*)(ws + OFF_Q);
  float* out = (float*)d_out;

  hipLaunchKernelGGL(k_xt, dim3(64, 8, 16), dim3(256), 0, stream,
                     x, xt, Wq, bq, Wk, bk, Wv, bv, Wr, br, gamma, beta, rm, rv,
                     wqkv, wrb, bqkv, scale, off2);
  hipLaunchKernelGGL(k_qkv, dim3(16, 3, 16), dim3(512), 0, stream, xt, wqkv, bqkv, qkv);
  hipLaunchKernelGGL(k_attn, dim3(4096), dim3(256), 0, stream, qkv, yb);
  hipLaunchKernelGGL(k_yt, dim3(64, 4, 16), dim3(256), 0, stream, yb, yt);
  hipLaunchKernelGGL(k_recon, dim3(32, 4, 16), dim3(256), 0, stream, yt, wrb, scale, off2, x, out);
}

// Round 8
// 209.332 us; speedup vs baseline: 1.0500x; 1.0244x over previous
//
#include <hip/hip_runtime.h>

// types
typedef __attribute__((ext_vector_type(8))) short bf16x8;
typedef __attribute__((ext_vector_type(4))) float f32x4;

#define DEVI static __device__ __forceinline__

DEVI unsigned short f2b(float f) {
  union { float f; unsigned u; } v; v.f = f;
  unsigned r = v.u + 0x7fffu + ((v.u >> 16) & 1u);
  return (unsigned short)(r >> 16);
}

typedef const __attribute__((address_space(1))) void* gas1_t;
typedef __attribute__((address_space(3))) void* las3_t;
#define GL16(g, l) __builtin_amdgcn_global_load_lds((gas1_t)(g), (las3_t)(l), 16, 0, 0)

#define WAITVM(N) asm volatile("s_waitcnt vmcnt(" #N ")" ::: "memory")
#define WAITLGKM  asm volatile("s_waitcnt lgkmcnt(0)" ::: "memory")
#define SCHEDBAR  __builtin_amdgcn_sched_barrier(0)

// ---- workspace layout (bytes) ----
#define OFF_WQKV  0ull          // 768*512*2
#define OFF_WR    786432ull     // 512*256*2
#define OFF_BQKV  1048576ull
#define OFF_SCALE 1051648ull
#define OFF_OFF2  1053696ull
#define OFF_XT    2097152ull    // xt bf16 [16][4096][512] = 64 MiB
#define OFF_YT    2097152ull    // yt bf16 [16][4096][256] = 32 MiB (reuses xt after qkv)
#define OFF_Y     35651584ull   // y  bf16 [16][256][4096] = 32 MiB
#define OFF_Q     69206016ull   // qkv bf16: q,k,v each 16777216 u16

// ---------------- P1: x [B][C][S] f32 -> xt [B][S][C] bf16  (+ fused weight prep) ----------------
__global__ __launch_bounds__(256) void k_xt(
    const float* __restrict__ x, unsigned short* __restrict__ xt,
    const float* __restrict__ Wq, const float* __restrict__ bq,
    const float* __restrict__ Wk, const float* __restrict__ bk,
    const float* __restrict__ Wv, const float* __restrict__ bv,
    const float* __restrict__ Wr, const float* __restrict__ br,
    const float* __restrict__ gamma, const float* __restrict__ beta,
    const float* __restrict__ rm, const float* __restrict__ rv,
    unsigned short* __restrict__ wqkv, unsigned short* __restrict__ wrb,
    float* __restrict__ bqkv, float* __restrict__ scale, float* __restrict__ off2)
{
  __shared__ unsigned short tile[64][72];
  const int t = threadIdx.x;
  const int bid = blockIdx.x + blockIdx.y * 64 + blockIdx.z * 512;

  if (bid < 1536) {
    int i = bid * 256 + t;
    if (i < 768 * 512) {
      int o = i >> 9, c = i & 511;
      float v = (o < 256) ? Wq[o * 512 + c] : (o < 512 ? Wk[(o - 256) * 512 + c] : Wv[(o - 512) * 512 + c]);
      wqkv[i] = f2b(v);
    }
    if (i < 512 * 256) wrb[i] = f2b(Wr[i]);
    if (i < 768) bqkv[i] = (i < 256) ? bq[i] : (i < 512 ? bk[i - 256] : bv[i - 512]);
    if (i < 512) {
      float inv = gamma[i] * rsqrtf(rv[i] + 1e-5f);
      scale[i] = inv;
      off2[i] = (br[i] - rm[i]) * inv + beta[i];
    }
  }

  const int b = blockIdx.z, c0 = blockIdx.y * 64, s0 = blockIdx.x * 64;
  const int r = t >> 2, cc = (t & 3) * 16;
  const float* src = x + ((size_t)b * 512 + c0 + r) * 4096 + s0 + cc;
  #pragma unroll
  for (int j = 0; j < 16; j += 4) {
    float4 v = *(const float4*)(src + j);
    tile[r][cc + j + 0] = f2b(v.x);
    tile[r][cc + j + 1] = f2b(v.y);
    tile[r][cc + j + 2] = f2b(v.z);
    tile[r][cc + j + 3] = f2b(v.w);
  }
  __syncthreads();
  unsigned short* dst = xt + ((size_t)b * 4096 + s0 + r) * 512 + c0 + cc;
  bf16x8 o0, o1;
  #pragma unroll
  for (int j = 0; j < 8; ++j) { o0[j] = tile[cc + j][r]; o1[j] = tile[cc + 8 + j][r]; }
  *(bf16x8*)(dst) = o0;
  *(bf16x8*)(dst + 8) = o1;
}

// ---------------- G1: QKV GEMM, 128x128, BK=64, ring-2, swizzled LDS, loads-upfront CMP ----------------
// (round-4 proven form: 2 blocks/CU, implicit inter-block overlap; no XCD swizzle, no setprio)
__global__ __launch_bounds__(256) void k_qkv(
    const unsigned short* __restrict__ xt, const unsigned short* __restrict__ wqkv,
    const float* __restrict__ bqkv, unsigned short* __restrict__ qkv)
{
  __shared__ unsigned short lds[2][2][8192];  // 64 KB
  const int b = blockIdx.z, o0 = blockIdx.y * 128, s0 = blockIdx.x * 128;
  const int t = threadIdx.x, w = t >> 6, l = t & 63;
  const int wm = w >> 1, wn = w & 1, lr = l & 15;
  const int lkE = (l >> 4) * 8;
  const int swE = (lr & 7) * 8;
  const int cp = (t & 7) ^ ((t >> 3) & 7);

  const unsigned short* Ag = wqkv + (size_t)(o0 + (t >> 3)) * 512 + cp * 8;
  const unsigned short* Bg = xt + ((size_t)b * 4096 + s0 + (t >> 3)) * 512 + cp * 8;

  const f32x4 z = {0.f, 0.f, 0.f, 0.f};
  f32x4 acc[4][4];
  #pragma unroll
  for (int i = 0; i < 4; ++i)
    #pragma unroll
    for (int j = 0; j < 4; ++j) acc[i][j] = z;

#define STG_Q(st, kt) do { \
    _Pragma("unroll") \
    for (int j = 0; j < 4; ++j) { \
      GL16(Ag + (kt) * 64 + j * 32 * 512, (char*)&lds[st][0][0] + j * 4096 + t * 16); \
      GL16(Bg + (kt) * 64 + j * 32 * 512, (char*)&lds[st][1][0] + j * 4096 + t * 16); \
    } \
  } while (0)

  // loads-upfront compute: all 16 ds_read, then 32 MFMA; reads provably retire
  // before the wave reaches the following barrier (every result feeds an MFMA issue).
#define CMP_Q(st) do { \
    const unsigned short* A  = &lds[st][0][0]; \
    const unsigned short* Bl = &lds[st][1][0]; \
    bf16x8 af[2][4], bfr[2][4]; \
    _Pragma("unroll") \
    for (int kc = 0; kc < 2; ++kc) { \
      const int kidx = (kc * 32 + lkE) ^ swE; \
      _Pragma("unroll") \
      for (int mi = 0; mi < 4; ++mi) af[kc][mi] = *(const bf16x8*)(A + (wm * 64 + mi * 16 + lr) * 64 + kidx); \
      _Pragma("unroll") \
      for (int ni = 0; ni < 4; ++ni) bfr[kc][ni] = *(const bf16x8*)(Bl + (wn * 64 + ni * 16 + lr) * 64 + kidx); \
    } \
    _Pragma("unroll") \
    for (int kc = 0; kc < 2; ++kc) \
      _Pragma("unroll") \
      for (int mi = 0; mi < 4; ++mi) \
        _Pragma("unroll") \
        for (int ni = 0; ni < 4; ++ni) \
          acc[mi][ni] = __builtin_amdgcn_mfma_f32_16x16x32_bf16(af[kc][mi], bfr[kc][ni], acc[mi][ni], 0, 0, 0); \
  } while (0)

  STG_Q(0, 0); STG_Q(1, 1);
  #pragma unroll
  for (int kt = 0; kt < 7; ++kt) {
    WAITVM(8);
    __builtin_amdgcn_s_barrier(); SCHEDBAR;
    CMP_Q(kt & 1);
    __builtin_amdgcn_s_barrier(); SCHEDBAR;
    if (kt + 2 < 8) STG_Q(kt & 1, kt + 2);
  }
  WAITVM(0);
  __builtin_amdgcn_s_barrier(); SCHEDBAR;
  CMP_Q(1);   // kt=7

  #pragma unroll
  for (int mi = 0; mi < 4; ++mi) {
    #pragma unroll
    for (int reg = 0; reg < 4; ++reg) {
      const int o = o0 + wm * 64 + mi * 16 + (l >> 4) * 4 + reg;
      const float bias = bqkv[o];
      const size_t base = (size_t)(o >> 8) * 16777216ull + ((size_t)b * 256 + (o & 255)) * 4096;
      #pragma unroll
      for (int ni = 0; ni < 4; ++ni) {
        const int s = s0 + wn * 64 + ni * 16 + lr;
        qkv[base + s] = f2b(acc[mi][ni][reg] + bias);
      }
    }
  }
#undef STG_Q
#undef CMP_Q
}

// ---------------- G2: per-group attention ----------------
__global__ __launch_bounds__(256) void k_attn(const unsigned short* __restrict__ qkv,
                                              unsigned short* __restrict__ yout)
{
  __shared__ unsigned short Vt[64][80];
  __shared__ unsigned short P[4][16][80];
  const int g = blockIdx.x;
  const unsigned short* qg = qkv + (size_t)g * 4096;
  const unsigned short* kg = qkv + 16777216ull + (size_t)g * 4096;
  const unsigned short* vg = qkv + 33554432ull + (size_t)g * 4096;
  const int t = threadIdx.x, w = t >> 6, l = t & 63;
  const int lr = l & 15, lk = (l >> 4) * 8;

  {
    const int j = t >> 2, c0 = (t & 3) * 16;
    bf16x8 a = *(const bf16x8*)(vg + j * 64 + c0);
    bf16x8 bb = *(const bf16x8*)(vg + j * 64 + c0 + 8);
    #pragma unroll
    for (int jj = 0; jj < 8; ++jj) { Vt[c0 + jj][j] = a[jj]; Vt[c0 + 8 + jj][j] = bb[jj]; }
  }

  const f32x4 z = {0.f, 0.f, 0.f, 0.f};
  bf16x8 qf[2];
  #pragma unroll
  for (int kc = 0; kc < 2; ++kc) qf[kc] = *(const bf16x8*)(qg + (w * 16 + lr) * 64 + kc * 32 + lk);
  f32x4 accS[4] = {z, z, z, z};
  __builtin_amdgcn_s_setprio(1);
  #pragma unroll
  for (int jt = 0; jt < 4; ++jt)
    #pragma unroll
    for (int kc = 0; kc < 2; ++kc) {
      bf16x8 kf = *(const bf16x8*)(kg + (jt * 16 + lr) * 64 + kc * 32 + lk);
      accS[jt] = __builtin_amdgcn_mfma_f32_16x16x32_bf16(qf[kc], kf, accS[jt], 0, 0, 0);
    }
  __builtin_amdgcn_s_setprio(0);

  #pragma unroll
  for (int reg = 0; reg < 4; ++reg) {
    float mx = fmaxf(fmaxf(accS[0][reg], accS[1][reg]), fmaxf(accS[2][reg], accS[3][reg]));
    #pragma unroll
    for (int m = 1; m < 16; m <<= 1) mx = fmaxf(mx, __shfl_xor(mx, m, 64));
    float e0 = __expf(accS[0][reg] - mx), e1 = __expf(accS[1][reg] - mx);
    float e2 = __expf(accS[2][reg] - mx), e3 = __expf(accS[3][reg] - mx);
    float sm = e0 + e1 + e2 + e3;
    #pragma unroll
    for (int m = 1; m < 16; m <<= 1) sm += __shfl_xor(sm, m, 64);
    const float rs = 1.f / sm;
    const int row = (l >> 4) * 4 + reg;
    P[w][row][0 * 16 + lr] = f2b(e0 * rs);
    P[w][row][1 * 16 + lr] = f2b(e1 * rs);
    P[w][row][2 * 16 + lr] = f2b(e2 * rs);
    P[w][row][3 * 16 + lr] = f2b(e3 * rs);
  }
  __syncthreads();

  bf16x8 pf[2];
  #pragma unroll
  for (int kc = 0; kc < 2; ++kc) pf[kc] = *(const bf16x8*)(&P[w][lr][kc * 32 + lk]);
  f32x4 accY[4] = {z, z, z, z};
  __builtin_amdgcn_s_setprio(1);
  #pragma unroll
  for (int nt = 0; nt < 4; ++nt)
    #pragma unroll
    for (int kc = 0; kc < 2; ++kc) {
      bf16x8 vf = *(const bf16x8*)(&Vt[nt * 16 + lr][kc * 32 + lk]);
      accY[nt] = __builtin_amdgcn_mfma_f32_16x16x32_bf16(pf[kc], vf, accY[nt], 0, 0, 0);
    }
  __builtin_amdgcn_s_setprio(0);

  unsigned short* yg = yout + (size_t)g * 4096;
  #pragma unroll
  for (int nt = 0; nt < 4; ++nt)
    #pragma unroll
    for (int reg = 0; reg < 4; ++reg) {
      const int i = w * 16 + (l >> 4) * 4 + reg;
      yg[i * 64 + nt * 16 + lr] = f2b(accY[nt][reg]);
    }
}

// ---------------- G2b: y [B][CR][S] -> yt [B][S][CR] ----------------
__global__ __launch_bounds__(256) void k_yt(const unsigned short* __restrict__ y, unsigned short* __restrict__ yt)
{
  __shared__ unsigned short tile[64][72];
  const int b = blockIdx.z, cr0 = blockIdx.y * 64, s0 = blockIdx.x * 64;
  const int t = threadIdx.x, r = t >> 2, c0 = (t & 3) * 16;
  const unsigned short* src = y + ((size_t)b * 256 + cr0 + r) * 4096 + s0 + c0;
  bf16x8 a = *(const bf16x8*)(src);
  bf16x8 bb = *(const bf16x8*)(src + 8);
  #pragma unroll
  for (int j = 0; j < 8; ++j) { tile[r][c0 + j] = a[j]; tile[r][c0 + 8 + j] = bb[j]; }
  __syncthreads();
  unsigned short* dst = yt + ((size_t)b * 4096 + s0 + r) * 256 + cr0 + c0;
  bf16x8 o0, o1;
  #pragma unroll
  for (int j = 0; j < 8; ++j) { o0[j] = tile[c0 + j][r]; o1[j] = tile[c0 + 8 + j][r]; }
  *(bf16x8*)(dst) = o0;
  *(bf16x8*)(dst + 8) = o1;
}

// ---------------- G3: recon GEMM + BN + residual, 128x128, BK=64, ring-2, loads-upfront CMP ----------------
__global__ __launch_bounds__(256) void k_recon(
    const unsigned short* __restrict__ yt, const unsigned short* __restrict__ wrb,
    const float* __restrict__ scale, const float* __restrict__ off2,
    const float* __restrict__ x, float* __restrict__ out)
{
  __shared__ unsigned short lds[2][2][8192];  // 64 KB
  const int b = blockIdx.z, o0 = blockIdx.y * 128, s0 = blockIdx.x * 128;
  const int t = threadIdx.x, w = t >> 6, l = t & 63;
  const int wm = w >> 1, wn = w & 1, lr = l & 15;
  const int lkE = (l >> 4) * 8;
  const int swE = (lr & 7) * 8;
  const int cp = (t & 7) ^ ((t >> 3) & 7);

  const unsigned short* Ag = wrb + (size_t)(o0 + (t >> 3)) * 256 + cp * 8;
  const unsigned short* Bg = yt + ((size_t)b * 4096 + s0 + (t >> 3)) * 256 + cp * 8;

  const f32x4 z = {0.f, 0.f, 0.f, 0.f};
  f32x4 acc[4][4];
  #pragma unroll
  for (int i = 0; i < 4; ++i)
    #pragma unroll
    for (int j = 0; j < 4; ++j) acc[i][j] = z;

#define STG_R(st, kt) do { \
    _Pragma("unroll") \
    for (int j = 0; j < 4; ++j) { \
      GL16(Ag + (kt) * 64 + j * 32 * 256, (char*)&lds[st][0][0] + j * 4096 + t * 16); \
      GL16(Bg + (kt) * 64 + j * 32 * 256, (char*)&lds[st][1][0] + j * 4096 + t * 16); \
    } \
  } while (0)

#define CMP_R(st) do { \
    const unsigned short* A  = &lds[st][0][0]; \
    const unsigned short* Bl = &lds[st][1][0]; \
    bf16x8 af[2][4], bfr[2][4]; \
    _Pragma("unroll") \
    for (int kc = 0; kc < 2; ++kc) { \
      const int kidx = (kc * 32 + lkE) ^ swE; \
      _Pragma("unroll") \
      for (int mi = 0; mi < 4; ++mi) af[kc][mi] = *(const bf16x8*)(A + (wm * 64 + mi * 16 + lr) * 64 + kidx); \
      _Pragma("unroll") \
      for (int ni = 0; ni < 4; ++ni) bfr[kc][ni] = *(const bf16x8*)(Bl + (wn * 64 + ni * 16 + lr) * 64 + kidx); \
    } \
    _Pragma("unroll") \
    for (int kc = 0; kc < 2; ++kc) \
      _Pragma("unroll") \
      for (int mi = 0; mi < 4; ++mi) \
        _Pragma("unroll") \
        for (int ni = 0; ni < 4; ++ni) \
          acc[mi][ni] = __builtin_amdgcn_mfma_f32_16x16x32_bf16(af[kc][mi], bfr[kc][ni], acc[mi][ni], 0, 0, 0); \
  } while (0)

  STG_R(0, 0); STG_R(1, 1);
  #pragma unroll
  for (int kt = 0; kt < 3; ++kt) {
    WAITVM(8);
    __builtin_amdgcn_s_barrier(); SCHEDBAR;
    CMP_R(kt & 1);
    __builtin_amdgcn_s_barrier(); SCHEDBAR;
    if (kt + 2 < 4) STG_R(kt & 1, kt + 2);
  }
  WAITVM(0);
  __builtin_amdgcn_s_barrier(); SCHEDBAR;
  CMP_R(1);   // kt=3

  // epilogue: out = acc*scale[o] + off2[o] + x
  #pragma unroll
  for (int mi = 0; mi < 4; ++mi) {
    #pragma unroll
    for (int reg = 0; reg < 4; ++reg) {
      const int o = o0 + wm * 64 + mi * 16 + (l >> 4) * 4 + reg;
      const float sc = scale[o], of = off2[o];
      const size_t base = ((size_t)b * 512 + o) * 4096;
      #pragma unroll
      for (int ni = 0; ni < 4; ++ni) {
        const int s = s0 + wn * 64 + ni * 16 + lr;
        const size_t idx = base + s;
        out[idx] = acc[mi][ni][reg] * sc + of + x[idx];
      }
    }
  }
#undef STG_R
#undef CMP_R
}

extern "C" void kernel_launch(void* const* d_in, const int* in_sizes, int n_in,
                              void* d_out, int out_size, void* d_ws, size_t ws_size,
                              hipStream_t stream)
{
  const float* x     = (const float*)d_in[0];
  const float* Wq    = (const float*)d_in[1];
  const float* bq    = (const float*)d_in[2];
  const float* Wk    = (const float*)d_in[3];
  const float* bk    = (const float*)d_in[4];
  const float* Wv    = (const float*)d_in[5];
  const float* bv    = (const float*)d_in[6];
  const float* Wr    = (const float*)d_in[7];
  const float* br    = (const float*)d_in[8];
  const float* gamma = (const float*)d_in[9];
  const float* beta  = (const float*)d_in[10];
  const float* rm    = (const float*)d_in[11];
  const float* rv    = (const float*)d_in[12];

  char* ws = (char*)d_ws;
  unsigned short* wqkv  = (unsigned short*)(ws + OFF_WQKV);
  unsigned short* wrb   = (unsigned short*)(ws + OFF_WR);
  float* bqkv  = (float*)(ws + OFF_BQKV);
  float* scale = (float*)(ws + OFF_SCALE);
  float* off2  = (float*)(ws + OFF_OFF2);
  unsigned short* xt  = (unsigned short*)(ws + OFF_XT);
  unsigned short* yt  = (unsigned short*)(ws + OFF_YT);
  unsigned short* yb  = (unsigned short*)(ws + OFF_Y);
  unsigned short* qkv = (unsigned short*)(ws + OFF_Q);
  float* out = (float*)d_out;

  hipLaunchKernelGGL(k_xt, dim3(64, 8, 16), dim3(256), 0, stream,
                     x, xt, Wq, bq, Wk, bk, Wv, bv, Wr, br, gamma, beta, rm, rv,
                     wqkv, wrb, bqkv, scale, off2);
  hipLaunchKernelGGL(k_qkv, dim3(32, 6, 16), dim3(256), 0, stream, xt, wqkv, bqkv, qkv);
  hipLaunchKernelGGL(k_attn, dim3(4096), dim3(256), 0, stream, qkv, yb);
  hipLaunchKernelGGL(k_yt, dim3(64, 4, 16), dim3(256), 0, stream, yb, yt);
  hipLaunchKernelGGL(k_recon, dim3(32, 4, 16), dim3(256), 0, stream, yt, wrb, scale, off2, x, out);
}